// Round 5
// baseline (101.298 us; speedup 1.0000x reference)
//
#include <hip/hip_runtime.h>
#include <math.h>

#define T_    128
#define LENM  32
#define NCOL  (8192 * 64)   // N*F = 524288 floats per timestep row

typedef float f2_t __attribute__((ext_vector_type(2)));

// Kernel 1: build ALIGNED compact weights Wc[128][32] in d_ws.
// Wc[t][j] multiplies source row (t-31+j); zero when that row < 0.
__global__ void build_w_kernel(const float* __restrict__ M_pad,
                               const float* __restrict__ M_big,
                               float* __restrict__ Wc) {
    int t = threadIdx.x;
    if (t >= T_) return;
    const float* src;
    int len, joff;
    if (t < LENM)       { src = M_pad + t * LENM;              len = t + 1; joff = LENM - 1 - t; }
    else if (t == LENM) { src = M_pad + (LENM - 1) * LENM;     len = LENM;  joff = 0; }
    else                { src = M_big + (t - LENM - 1) * LENM; len = LENM;  joff = 0; }

    float m = -3.4e38f;
    for (int j = 0; j < len; ++j) m = fmaxf(m, src[j]);
    float e[LENM];
    float s = 0.f;
    for (int j = 0; j < len; ++j) { e[j] = expf(src[j] - m); s += e[j]; }
    float inv = 1.f / s;
    for (int j = 0; j < LENM; ++j) Wc[t * LENM + j] = 0.f;
    for (int j = 0; j < len; ++j)  Wc[t * LENM + joff + j] = e[j] * inv;
}

typedef float f4_t __attribute__((ext_vector_type(4)));

// One pipeline step for output row R (compile-time). Chunk K = R/32 uses
// window buffer CUR=(K&1?B:A), previous chunk's buffer is PRV. Issues the
// global load of row R+8 into its statically-known slot, then computes
// output R from 32 banded taps (prefix-zero taps skipped at compile time)
// and stores it nontemporally.
template<int R>
__device__ __forceinline__ void step(const f2_t* __restrict__ xp,
                                     f2_t* __restrict__ op,
                                     const f4_t* w4,
                                     f2_t (&A)[LENM], f2_t (&B)[LENM]) {
    constexpr int K     = R / LENM;
    constexpr int i_    = R % LENM;
    constexpr int jmin_ = (R < LENM) ? (LENM - 1 - i_) : 0;
    f2_t (&CUR)[LENM] = (K & 1) ? B : A;
    f2_t (&PRV)[LENM] = (K & 1) ? A : B;
    const size_t rs = NCOL / 2;   // row stride in f2 units

    if constexpr (R + 8 < T_) {
        f2_t ld = xp[(size_t)(R + 8) * rs];
        if constexpr (i_ < LENM - 8) CUR[i_ + 8] = ld;          // same chunk
        else                         PRV[i_ - (LENM - 8)] = ld; // next chunk's buffer
    }

    f2_t acc; acc.x = 0.f; acc.y = 0.f;
#pragma unroll
    for (int q = 0; q < 8; ++q) {
        if (q * 4 + 3 >= jmin_) {            // folds: q, jmin_ are constants
            f4_t w = w4[R * 8 + q];
#pragma unroll
            for (int m = 0; m < 4; ++m) {
                const int j = q * 4 + m;
                if (j >= jmin_) {
                    f2_t xv = (j < LENM - 1 - i_) ? PRV[i_ + 1 + j]
                                                  : CUR[i_ + j - (LENM - 1)];
                    float wm = (m == 0) ? w.x : (m == 1) ? w.y
                             : (m == 2) ? w.z : w.w;
                    acc.x = fmaf(wm, xv.x, acc.x);
                    acc.y = fmaf(wm, xv.y, acc.y);
                }
            }
        }
    }
    __builtin_nontemporal_store(acc, &op[(size_t)R * rs]);
}

template<int R>
__device__ __forceinline__ void run_steps(const f2_t* __restrict__ xp,
                                          f2_t* __restrict__ op,
                                          const f4_t* w4,
                                          f2_t (&A)[LENM], f2_t (&B)[LENM]) {
    if constexpr (R < T_) {
        step<R>(xp, op, w4, A, B);
        run_steps<R + 1>(xp, op, w4, A, B);
    }
}

// Kernel 2: sliding-window mix. Each thread owns 2 adjacent columns (float2)
// to keep the live window ~105 VGPR -> 4 waves/SIMD (16 waves/CU) for TLP.
// Flat 128-step software pipeline with 8-row lookahead; ping-pong register
// windows A/B, all indices compile-time (template recursion).
__global__ __launch_bounds__(256, 4) void band_mix_kernel(
    const float* __restrict__ X,
    const float* __restrict__ Wc,
    float* __restrict__ out) {
    __shared__ f4_t w4[T_ * LENM / 4];   // 1024 f4 = 16 KB
    for (int i = threadIdx.x; i < T_ * LENM / 4; i += 256)
        w4[i] = reinterpret_cast<const f4_t*>(Wc)[i];
    __syncthreads();

    const int c = (blockIdx.x * 256 + threadIdx.x) * 2;
    const f2_t* xp = reinterpret_cast<const f2_t*>(X + c);
    f2_t* op = reinterpret_cast<f2_t*>(out + c);
    const size_t rs = NCOL / 2;

    f2_t A[LENM], B[LENM];
    // prologue: rows 0..7 into A (chunk 0 never reads PRV; B needs no init)
#pragma unroll
    for (int i = 0; i < 8; ++i) A[i] = xp[(size_t)i * rs];

    run_steps<0>(xp, op, w4, A, B);
}

extern "C" void kernel_launch(void* const* d_in, const int* in_sizes, int n_in,
                              void* d_out, int out_size, void* d_ws, size_t ws_size,
                              hipStream_t stream) {
    const float* X     = (const float*)d_in[0];
    const float* M_pad = (const float*)d_in[1];
    const float* M_big = (const float*)d_in[2];
    float* out = (float*)d_out;
    float* Wc  = (float*)d_ws;   // 128*32*4 = 16 KB scratch

    build_w_kernel<<<1, 128, 0, stream>>>(M_pad, M_big, Wc);
    band_mix_kernel<<<NCOL / 2 / 256, 256, 0, stream>>>(X, Wc, out);
}

// Round 6
// 100.309 us; speedup vs baseline: 1.0099x; 1.0099x over previous
//
#include <hip/hip_runtime.h>
#include <math.h>

#define T_    128
#define LENM  32
#define NCOL  (8192 * 64)   // N*F = 524288 floats per timestep row

typedef float f4_t __attribute__((ext_vector_type(4)));

// Kernel 1: build ALIGNED compact weights Wc[128][32] in d_ws.
// Wc[t][j] multiplies source row (t-31+j); zero when that row < 0.
__global__ void build_w_kernel(const float* __restrict__ M_pad,
                               const float* __restrict__ M_big,
                               float* __restrict__ Wc) {
    int t = threadIdx.x;
    if (t >= T_) return;
    const float* src;
    int len, joff;
    if (t < LENM)       { src = M_pad + t * LENM;              len = t + 1; joff = LENM - 1 - t; }
    else if (t == LENM) { src = M_pad + (LENM - 1) * LENM;     len = LENM;  joff = 0; }
    else                { src = M_big + (t - LENM - 1) * LENM; len = LENM;  joff = 0; }

    float m = -3.4e38f;
    for (int j = 0; j < len; ++j) m = fmaxf(m, src[j]);
    float e[LENM];
    float s = 0.f;
    for (int j = 0; j < len; ++j) { e[j] = expf(src[j] - m); s += e[j]; }
    float inv = 1.f / s;
    for (int j = 0; j < LENM; ++j) Wc[t * LENM + j] = 0.f;
    for (int j = 0; j < len; ++j)  Wc[t * LENM + joff + j] = e[j] * inv;
}

#define LOOKAHEAD 8

// One pipeline step for output row R (compile-time). Chunk K = R/32 uses
// window buffer CUR=(K&1?B:A), previous chunk's buffer is PRV. Issues the
// global load of row R+LOOKAHEAD, then a sched_barrier(0) pins it (the
// compiler otherwise sinks loads to first use, collapsing in-flight depth
// to 1 — measured round 5: VGPR_Count=52 proves the window was not held).
template<int R>
__device__ __forceinline__ void step(const f4_t* __restrict__ xp,
                                     f4_t* __restrict__ op,
                                     const f4_t* w4,
                                     f4_t (&A)[LENM], f4_t (&B)[LENM]) {
    constexpr int K     = R / LENM;
    constexpr int i_    = R % LENM;
    constexpr int jmin_ = (R < LENM) ? (LENM - 1 - i_) : 0;
    f4_t (&CUR)[LENM] = (K & 1) ? B : A;
    f4_t (&PRV)[LENM] = (K & 1) ? A : B;
    const size_t rs = NCOL / 4;   // row stride in f4 units

    if constexpr (R + LOOKAHEAD < T_) {
        f4_t ld = xp[(size_t)(R + LOOKAHEAD) * rs];
        if constexpr (i_ < LENM - LOOKAHEAD) CUR[i_ + LOOKAHEAD] = ld;
        else                                 PRV[i_ - (LENM - LOOKAHEAD)] = ld;
    }
    // Pin the load above this point; keep LOOKAHEAD loads in flight.
    __builtin_amdgcn_sched_barrier(0);

    f4_t acc; acc.x = 0.f; acc.y = 0.f; acc.z = 0.f; acc.w = 0.f;
#pragma unroll
    for (int q = 0; q < 8; ++q) {
        if (q * 4 + 3 >= jmin_) {            // folds: q, jmin_ are constants
            f4_t w = w4[R * 8 + q];
#pragma unroll
            for (int m = 0; m < 4; ++m) {
                const int j = q * 4 + m;
                if (j >= jmin_) {
                    f4_t xv = (j < LENM - 1 - i_) ? PRV[i_ + 1 + j]
                                                  : CUR[i_ + j - (LENM - 1)];
                    float wm = (m == 0) ? w.x : (m == 1) ? w.y
                             : (m == 2) ? w.z : w.w;
                    acc.x = fmaf(wm, xv.x, acc.x);
                    acc.y = fmaf(wm, xv.y, acc.y);
                    acc.z = fmaf(wm, xv.z, acc.z);
                    acc.w = fmaf(wm, xv.w, acc.w);
                }
            }
        }
    }
    __builtin_nontemporal_store(acc, &op[(size_t)R * rs]);
}

template<int R>
__device__ __forceinline__ void run_steps(const f4_t* __restrict__ xp,
                                          f4_t* __restrict__ op,
                                          const f4_t* w4,
                                          f4_t (&A)[LENM], f4_t (&B)[LENM]) {
    if constexpr (R < T_) {
        step<R>(xp, op, w4, A, B);
        run_steps<R + 1>(xp, op, w4, A, B);
    }
}

// Kernel 2: sliding-window mix. Each thread owns 4 adjacent columns (float4).
// Flat 128-step software pipeline, 8-row lookahead enforced by
// sched_barrier(0); ping-pong register windows A/B, all indices static.
__global__ __launch_bounds__(256, 2) void band_mix_kernel(
    const float* __restrict__ X,
    const float* __restrict__ Wc,
    float* __restrict__ out) {
    __shared__ f4_t w4[T_ * LENM / 4];   // 1024 f4 = 16 KB
    for (int i = threadIdx.x; i < T_ * LENM / 4; i += 256)
        w4[i] = reinterpret_cast<const f4_t*>(Wc)[i];
    __syncthreads();

    const int c = (blockIdx.x * 256 + threadIdx.x) * 4;
    const f4_t* xp = reinterpret_cast<const f4_t*>(X + c);
    f4_t* op = reinterpret_cast<f4_t*>(out + c);
    const size_t rs = NCOL / 4;

    f4_t A[LENM], B[LENM];
    // prologue: rows 0..7 into A (chunk 0 never reads PRV; B needs no init)
#pragma unroll
    for (int i = 0; i < LOOKAHEAD; ++i) A[i] = xp[(size_t)i * rs];
    __builtin_amdgcn_sched_barrier(0);

    run_steps<0>(xp, op, w4, A, B);
}

extern "C" void kernel_launch(void* const* d_in, const int* in_sizes, int n_in,
                              void* d_out, int out_size, void* d_ws, size_t ws_size,
                              hipStream_t stream) {
    const float* X     = (const float*)d_in[0];
    const float* M_pad = (const float*)d_in[1];
    const float* M_big = (const float*)d_in[2];
    float* out = (float*)d_out;
    float* Wc  = (float*)d_ws;   // 128*32*4 = 16 KB scratch

    build_w_kernel<<<1, 128, 0, stream>>>(M_pad, M_big, Wc);
    band_mix_kernel<<<NCOL / 4 / 256, 256, 0, stream>>>(X, Wc, out);
}